// Round 1
// baseline (670.574 us; speedup 1.0000x reference)
//
#include <hip/hip_runtime.h>
#include <stdint.h>

#define DHID 64  // hidden dim, fixed by problem

static inline size_t align256(size_t x) { return (x + 255) & ~(size_t)255; }

// ---------------- CSR build ----------------

__global__ void zero_i32(int* __restrict__ p, int n) {
  int i = blockIdx.x * blockDim.x + threadIdx.x;
  if (i < n) p[i] = 0;
}

__global__ void zero_f32(float* __restrict__ p, size_t n) {
  size_t i = (size_t)blockIdx.x * blockDim.x + threadIdx.x;
  if (i < n) p[i] = 0.f;
}

__global__ void hist_k(const int* __restrict__ row, int* __restrict__ count, int nnz) {
  int e = blockIdx.x * blockDim.x + threadIdx.x;
  if (e < nnz) atomicAdd(&count[row[e]], 1);
}

// scan over n counts, chunked at 2048 elems/block (8 per thread, 256 threads)
__global__ void scan1_k(const int* __restrict__ count, int* __restrict__ bsum, int n) {
  __shared__ int lds[4];
  int base = blockIdx.x * 2048 + threadIdx.x * 8;
  int s = 0;
#pragma unroll
  for (int i = 0; i < 8; ++i) { int idx = base + i; if (idx < n) s += count[idx]; }
#pragma unroll
  for (int off = 32; off > 0; off >>= 1) s += __shfl_down(s, off);
  if ((threadIdx.x & 63) == 0) lds[threadIdx.x >> 6] = s;
  __syncthreads();
  if (threadIdx.x == 0) bsum[blockIdx.x] = lds[0] + lds[1] + lds[2] + lds[3];
}

// single wave: exclusive-scan the (<=64) block sums; write total to rowstart[n]/cursor[n]
__global__ void scan2_k(int* __restrict__ bsum, int nb, int* __restrict__ rowstart,
                        int* __restrict__ cursor, int n) {
  int lane = threadIdx.x;
  int v = (lane < nb) ? bsum[lane] : 0;
  int incl = v;
#pragma unroll
  for (int off = 1; off < 64; off <<= 1) {
    int t = __shfl_up(incl, off);
    if (lane >= off) incl += t;
  }
  if (lane < nb) bsum[lane] = incl - v;          // exclusive block offset
  if (lane == 63) { rowstart[n] = incl; cursor[n] = incl; }  // total = nnz
}

__global__ void scan3_k(const int* __restrict__ count, const int* __restrict__ bsum,
                        int* __restrict__ rowstart, int* __restrict__ cursor, int n) {
  __shared__ int wsum[4];
  int base = blockIdx.x * 2048 + threadIdx.x * 8;
  int vals[8];
  int s = 0;
#pragma unroll
  for (int i = 0; i < 8; ++i) { int idx = base + i; vals[i] = (idx < n) ? count[idx] : 0; s += vals[i]; }
  int lane = threadIdx.x & 63, wid = threadIdx.x >> 6;
  int incl = s;
#pragma unroll
  for (int off = 1; off < 64; off <<= 1) {
    int t = __shfl_up(incl, off);
    if (lane >= off) incl += t;
  }
  if (lane == 63) wsum[wid] = incl;
  __syncthreads();
  int run = bsum[blockIdx.x] + (incl - s);
  for (int w = 0; w < wid; ++w) run += wsum[w];
#pragma unroll
  for (int i = 0; i < 8; ++i) {
    int idx = base + i;
    if (idx < n) { rowstart[idx] = run; cursor[idx] = run; }
    run += vals[i];
  }
}

__global__ void scatter_k(const int* __restrict__ row, const int* __restrict__ col,
                          const float* __restrict__ val, int* __restrict__ cursor,
                          int* __restrict__ col_s, float* __restrict__ val_s, int nnz) {
  int e = blockIdx.x * blockDim.x + threadIdx.x;
  if (e < nnz) {
    int pos = atomicAdd(&cursor[row[e]], 1);
    col_s[pos] = col[e];
    val_s[pos] = val[e];
  }
}

// ---------------- SpMM: one wave per row, lane = column ----------------

__global__ void spmm_k(const int* __restrict__ rowstart, const int* __restrict__ col_s,
                       const float* __restrict__ val_s, const float* __restrict__ x,
                       float* __restrict__ y, int n) {
  int wave = (blockIdx.x * blockDim.x + threadIdx.x) >> 6;
  int lane = threadIdx.x & 63;
  if (wave >= n) return;
  int start = rowstart[wave], end = rowstart[wave + 1];
  float acc = 0.f;
  for (int j = start; j < end; j += 64) {
    int cnt = min(64, end - j);
    int c = 0; float v = 0.f;
    if (lane < cnt) { c = col_s[j + lane]; v = val_s[j + lane]; }
    int k = 0;
    // 4x unroll: 4 independent 256B gathers in flight per wave
    for (; k + 4 <= cnt; k += 4) {
      int   c0 = __shfl(c, k),   c1 = __shfl(c, k + 1), c2 = __shfl(c, k + 2), c3 = __shfl(c, k + 3);
      float v0 = __shfl(v, k),   v1 = __shfl(v, k + 1), v2 = __shfl(v, k + 2), v3 = __shfl(v, k + 3);
      float x0 = x[(size_t)c0 * DHID + lane];
      float x1 = x[(size_t)c1 * DHID + lane];
      float x2 = x[(size_t)c2 * DHID + lane];
      float x3 = x[(size_t)c3 * DHID + lane];
      acc += v0 * x0; acc += v1 * x1; acc += v2 * x2; acc += v3 * x3;
    }
    for (; k < cnt; ++k) {
      int ck = __shfl(c, k);
      float vk = __shfl(v, k);
      acc += vk * x[(size_t)ck * DHID + lane];
    }
  }
  y[(size_t)wave * DHID + lane] = acc;
}

// ---------------- fallback: atomic SpMM (if ws too small) ----------------

__global__ void spmm_atomic_k(const int* __restrict__ row, const int* __restrict__ col,
                              const float* __restrict__ val, const float* __restrict__ x,
                              float* __restrict__ y, int nnz) {
  int wave = (blockIdx.x * blockDim.x + threadIdx.x) >> 6;
  int lane = threadIdx.x & 63;
  if (wave >= nnz) return;
  int r = row[wave]; int c = col[wave]; float v = val[wave];
  atomicAdd(&y[(size_t)r * DHID + lane], v * x[(size_t)c * DHID + lane]);
}

// ---------------- epilogue: summed = e0+e1+e2, copy e0 ----------------

__global__ void sum_k(const float4* __restrict__ e0, const float4* __restrict__ e1,
                      const float4* __restrict__ e2, float4* __restrict__ summed,
                      float4* __restrict__ e0out, int n4) {
  int i = blockIdx.x * blockDim.x + threadIdx.x;
  if (i < n4) {
    float4 a = e0[i], b = e1[i], c = e2[i];
    float4 s;
    s.x = a.x + b.x + c.x;
    s.y = a.y + b.y + c.y;
    s.z = a.z + b.z + c.z;
    s.w = a.w + b.w + c.w;
    summed[i] = s;
    e0out[i] = a;
  }
}

extern "C" void kernel_launch(void* const* d_in, const int* in_sizes, int n_in,
                              void* d_out, int out_size, void* d_ws, size_t ws_size,
                              hipStream_t stream) {
  const int*   row = (const int*)d_in[0];
  const int*   col = (const int*)d_in[1];
  const float* val = (const float*)d_in[2];
  const float* emb = (const float*)d_in[3];
  int nnz = in_sizes[0];
  int n   = in_sizes[3] / DHID;
  size_t ND = (size_t)n * DHID;

  float* out    = (float*)d_out;
  float* summed = out;
  float* e0o    = out + ND;
  float* e1     = out + 2 * ND;
  float* e2     = out + 3 * ND;

  int nb = (n + 2047) / 2048;

  // carve workspace
  size_t o0 = 0;
  size_t count_off    = o0; o0 += align256((size_t)(n + 1) * 4);
  size_t rowstart_off = o0; o0 += align256((size_t)(n + 1) * 4);
  size_t cursor_off   = o0; o0 += align256((size_t)(n + 1) * 4);
  size_t bsum_off     = o0; o0 += align256(256 * 4);
  size_t cols_off     = o0; o0 += align256((size_t)nnz * 4);
  size_t vals_off     = o0; o0 += align256((size_t)nnz * 4);
  size_t need = o0;

  bool use_csr = (ws_size >= need) && (nb <= 64);

  int eb = (nnz + 255) / 256;                       // edge-parallel blocks
  int wb = (int)(((size_t)nnz * 64 + 255) / 256);   // wave-per-edge blocks
  int rb = (int)((ND * 1 /*waves=n*/ + 255) / 256); // wave-per-row blocks: n*64 threads
  int n4 = (int)(ND / 4);
  int sb = (n4 + 255) / 256;

  if (use_csr) {
    uint8_t* w = (uint8_t*)d_ws;
    int*   count    = (int*)(w + count_off);
    int*   rowstart = (int*)(w + rowstart_off);
    int*   cursor   = (int*)(w + cursor_off);
    int*   bsum     = (int*)(w + bsum_off);
    int*   col_s    = (int*)(w + cols_off);
    float* val_s    = (float*)(w + vals_off);

    zero_i32<<<(n + 255) / 256, 256, 0, stream>>>(count, n);
    hist_k<<<eb, 256, 0, stream>>>(row, count, nnz);
    scan1_k<<<nb, 256, 0, stream>>>(count, bsum, n);
    scan2_k<<<1, 64, 0, stream>>>(bsum, nb, rowstart, cursor, n);
    scan3_k<<<nb, 256, 0, stream>>>(count, bsum, rowstart, cursor, n);
    scatter_k<<<eb, 256, 0, stream>>>(row, col, val, cursor, col_s, val_s, nnz);

    spmm_k<<<rb, 256, 0, stream>>>(rowstart, col_s, val_s, emb, e1, n);
    spmm_k<<<rb, 256, 0, stream>>>(rowstart, col_s, val_s, e1, e2, n);
  } else {
    zero_f32<<<(int)((ND + 255) / 256), 256, 0, stream>>>(e1, ND);
    spmm_atomic_k<<<wb, 256, 0, stream>>>(row, col, val, emb, e1, nnz);
    zero_f32<<<(int)((ND + 255) / 256), 256, 0, stream>>>(e2, ND);
    spmm_atomic_k<<<wb, 256, 0, stream>>>(row, col, val, e1, e2, nnz);
  }

  sum_k<<<sb, 256, 0, stream>>>((const float4*)emb, (const float4*)e1,
                                (const float4*)e2, (float4*)summed,
                                (float4*)e0o, n4);
}